// Round 6
// baseline (64.537 us; speedup 1.0000x reference)
//
#include <hip/hip_runtime.h>
#include <stdint.h>

// Problem constants (fixed by setup_inputs)
#define NB 16
#define NTF 4096      // frames T
#define ND 512        // feature dim D
#define NS 8192       // note_size (= 2*T)
#define NCOL 40       // 5 + 10 + 25 output columns
#define ROWSB 128     // rows per block (R=2 per lane)
#define BLOCK 512     // 8 waves
#define CPW 5         // cols per wave
#define CD 32         // chunk depth (floats of d)
#define NCH 16        // 512 / 32
#define LGS 132       // Lg row stride (128 + 4)

typedef float v4f  __attribute__((ext_vector_type(4)));
typedef float v16f __attribute__((ext_vector_type(16)));

// W pack (same as round 5): Wp3[(u*8 + w)*20 + c*4 + dl] = W[d = u*4+dl][col = w*5+c]
// -> per (wave w, 4-d unit u) slice is 20 contiguous floats (80 B):
//    one s_load_dwordx16 + one s_load_dwordx4.
extern "C" __global__ void pack_w_kernel(const float* __restrict__ Wg,
                                         const float* __restrict__ Wt,
                                         const float* __restrict__ Wf,
                                         float* __restrict__ Wp3)
{
    int o = blockIdx.x * 256 + threadIdx.x;
    if (o >= NCOL * ND) return;
    int s20 = o / 20, r = o % 20;
    int c = r >> 2, dl = r & 3;
    int u = s20 >> 3, w = s20 & 7;
    int d = u * 4 + dl, col = w * 5 + c;
    float v;
    if (col < 5)       v = Wg[d * 5  + col];
    else if (col < 15) v = Wt[d * 10 + (col - 5)];
    else               v = Wf[d * 25 + (col - 15)];
    Wp3[o] = v;
}

#define GLDS(gp, lp) __builtin_amdgcn_global_load_lds( \
    (const __attribute__((address_space(1))) unsigned int*)(gp), \
    (__attribute__((address_space(3))) unsigned int*)(lp), 16, 0, 0)

// W element at flat index 4c+dl from the 20-float bank {C16, C4}
#define WEL(C16, C4, c, dl) \
    ((4*(c)+(dl)) < 16 ? (C16)[4*(c)+(dl)] : (C4)[4*(c)+(dl)-16])

// One pipeline sub-step (4 d-values, 2 rows): wait current bank -> prefetch
// next bank (scalar pipe) -> prefetch next x4 pair (LDS) -> 40 FMAs.
#define SUB(S, C16, C4, N16, N4, PF) do {                                     \
    asm volatile("s_waitcnt lgkmcnt(0)" : "+s"(C16), "+s"(C4) :: "memory");   \
    if (PF) {                                                                 \
        asm volatile("s_load_dwordx16 %0, %2, %3\n\t"                         \
                     "s_load_dwordx4 %1, %2, %4"                              \
            : "=s"(N16), "=s"(N4)                                             \
            : "s"(wch + ((((S)+1) >> 3) * 1280)),                             \
              "i"((((S)+1) & 7) * 640), "i"(((((S)+1) & 7) * 640) + 64));     \
    }                                                                         \
    v4f xc0 = xn0, xc1 = xn1;                                                 \
    if ((S) < 7) {                                                            \
        xn0 = *(const v4f*)(xb + (size_t)(((S)+1)*128 + lane) * 4);           \
        xn1 = *(const v4f*)(xb + (size_t)(((S)+1)*128 + 64 + lane) * 4);      \
    }                                                                         \
    _Pragma("unroll")                                                         \
    for (int c = 0; c < CPW; ++c) {                                           \
        float a0 = acc0[c], a1 = acc1[c];                                     \
        a0 = fmaf(xc0.x, WEL(C16, C4, c, 0), a0);                             \
        a1 = fmaf(xc1.x, WEL(C16, C4, c, 0), a1);                             \
        a0 = fmaf(xc0.y, WEL(C16, C4, c, 1), a0);                             \
        a1 = fmaf(xc1.y, WEL(C16, C4, c, 1), a1);                             \
        a0 = fmaf(xc0.z, WEL(C16, C4, c, 2), a0);                             \
        a1 = fmaf(xc1.z, WEL(C16, C4, c, 2), a1);                             \
        a0 = fmaf(xc0.w, WEL(C16, C4, c, 3), a0);                             \
        a1 = fmaf(xc1.w, WEL(C16, C4, c, 3), a1);                             \
        acc0[c] = a0; acc1[c] = a1;                                           \
    }                                                                         \
} while (0)

extern "C" __global__ void __launch_bounds__(BLOCK, 4)
hier_main(const float* __restrict__ x,
          const float* __restrict__ bg, const float* __restrict__ bt,
          const float* __restrict__ bf,
          const float* __restrict__ Wp3, float* __restrict__ out)
{
    // chunk = 128 rows x 32 d = 16 KB; slot = dq*128 + row (float4 units)
    __shared__ __align__(16) float xs[3][ROWSB * CD];   // 48 KB
    __shared__ float Lg[NCOL * LGS];                    // logits [c][row], 21.1 KB

    const int t    = threadIdx.x;
    const int lane = t & 63;
    const int w    = t >> 6;                            // wave 0..7
    const int row0 = blockIdx.x * ROWSB;

    // uniform-by-construction scalars for the SGPR paths
    const int wu      = __builtin_amdgcn_readfirstlane(w);
    const float* Wp3w = Wp3 + wu * 20;                  // wave's W stream base

    float acc0[CPW], acc1[CPW];
#pragma unroll
    for (int c = 0; c < CPW; ++c) { acc0[c] = 0.f; acc1[c] = 0.f; }

    // stage: wave w issues 2 GLDS (1KB each): j = w and w+8; j-th instr covers
    // slots [j*64, j*64+64) = (dq = j>>1, rowhalf = j&1). Dest linear: j*1024 B.
    auto stage = [&](int ch_, int p_) {
#pragma unroll
        for (int k = 0; k < 2; ++k) {
            const int j  = w + k * 8;                   // 0..15
            const int dq = j >> 1;
            const int rh = j & 1;
            const float* gp = x + (size_t)(row0 + rh * 64 + lane) * ND + ch_ * CD + dq * 4;
            GLDS(gp, (char*)&xs[p_][0] + (size_t)j * 1024);
        }
    };

    // W bank registers (20 floats each)
    v16f bA16, bB16;
    v4f  bA4,  bB4;

    // prologue: x chunks 0,1 in flight (4 GLDS); W bank A (sub 0) in flight
    stage(0, 0);
    stage(1, 1);
    asm volatile("s_load_dwordx16 %0, %2, 0\n\t"
                 "s_load_dwordx4 %1, %2, 64"
                 : "=s"(bA16), "=s"(bA4) : "s"(Wp3w));

    int pc = 0;
    for (int ch = 0; ch < NCH; ++ch) {
        // own stage(ch) landed (stage(ch+1)'s 2 may stay in flight)
        if (ch < NCH - 1) asm volatile("s_waitcnt vmcnt(2)" ::: "memory");
        else              asm volatile("s_waitcnt vmcnt(0)" ::: "memory");
        __builtin_amdgcn_s_barrier();       // all waves' slices of chunk ch visible
        __builtin_amdgcn_sched_barrier(0);
        if (ch < NCH - 2) {
            int ps = pc + 2; if (ps >= 3) ps -= 3;
            stage(ch + 2, ps);              // overwrites buffer consumed at ch-1: safe past barrier
        }
        __builtin_amdgcn_sched_barrier(0);

        const float* xb  = &xs[pc][0];
        const float* wch = Wp3w + (size_t)ch * 1280;    // uniform: this chunk's W base
        v4f xn0 = *(const v4f*)(xb + (size_t)lane * 4);            // sub 0, row lane
        v4f xn1 = *(const v4f*)(xb + (size_t)(64 + lane) * 4);     // sub 0, row 64+lane

        const bool pf7 = (ch < NCH - 1);    // last global prefetch would be OOB
        SUB(0, bA16, bA4, bB16, bB4, true);
        SUB(1, bB16, bB4, bA16, bA4, true);
        SUB(2, bA16, bA4, bB16, bB4, true);
        SUB(3, bB16, bB4, bA16, bA4, true);
        SUB(4, bA16, bA4, bB16, bB4, true);
        SUB(5, bB16, bB4, bA16, bA4, true);
        SUB(6, bA16, bA4, bB16, bB4, true);
        SUB(7, bB16, bB4, bA16, bA4, pf7);

        pc = (pc + 1 == 3) ? 0 : pc + 1;
    }

    // ---- share logits: Lg[col][row] (lane-consecutive: conflict-free) ----
#pragma unroll
    for (int c = 0; c < CPW; ++c) {
        Lg[(w * CPW + c) * LGS + lane]      = acc0[c];
        Lg[(w * CPW + c) * LGS + 64 + lane] = acc1[c];
    }
    __syncthreads();

    // ---- phase A: per-row bias + hierarchical argmax chain (threads 0..127) ----
    if (t < ROWSB) {
        constexpr int TOWN[10] = {0,1,2,2,2,3,3,3,4,4};
        constexpr int FOWN[25] = {0,1,2,2,2,3,3,3,3,3,3,3,3,4,9,6,8,5,7,1,3,3,3,9,3};
        const int r = t;
        float gl[5]; int gp = 0; float gbest = -INFINITY;
#pragma unroll
        for (int c = 0; c < 5; ++c) {
            float v = Lg[c * LGS + r] + bg[c];
            gl[c] = v;
            if (v > gbest) { gbest = v; gp = c; }   // strict > == jnp.argmax first-max
        }
        float tl[10]; int tp = 0; float tbest = -INFINITY;
#pragma unroll
        for (int k = 0; k < 10; ++k) {
            float v = (Lg[(5 + k) * LGS + r] + bt[k]) * ((TOWN[k] == gp) ? 1.f : 0.f);
            tl[k] = v;
            if (v > tbest) { tbest = v; tp = k; }
        }
#pragma unroll
        for (int c = 0; c < 5; ++c)  Lg[c * LGS + r] = gl[c];
#pragma unroll
        for (int k = 0; k < 10; ++k) Lg[(5 + k) * LGS + r] = tl[k];
#pragma unroll
        for (int f = 0; f < 25; ++f) {
            float v = (Lg[(15 + f) * LGS + r] + bf[f]) * ((FOWN[f] == tp) ? 1.f : 0.f);
            Lg[(15 + f) * LGS + r] = v;
        }
    }
    __syncthreads();

    // ---- phase B: FULLY COALESCED linear stores (consecutive t -> consecutive
    // floats): each 128B line written back-to-back by one wave ----
    const int b   = row0 >> 12;
    const int tt0 = row0 & (NTF - 1);

    {   // group_up [B][S][5]: 256 frames x 5 = 1280 floats
        float* og = out + ((size_t)b * NS + 2 * (size_t)tt0) * 5;
        for (int i = t; i < 1280; i += BLOCK) {
            int s = i / 5, c = i - s * 5;
            og[i] = Lg[c * LGS + (s >> 1)];
        }
    }
    {   // tech_up [B][S][10]: 2560 floats
        float* ot = out + (size_t)NB * NS * 5 + ((size_t)b * NS + 2 * (size_t)tt0) * 10;
        for (int i = t; i < 2560; i += BLOCK) {
            int s = i / 10, c = i - s * 10;
            ot[i] = Lg[(5 + c) * LGS + (s >> 1)];
        }
    }
    {   // final_up [B][S][25]: 6400 floats
        float* of = out + (size_t)NB * NS * 15 + ((size_t)b * NS + 2 * (size_t)tt0) * 25;
        for (int i = t; i < 6400; i += BLOCK) {
            int s = i / 25, c = i - s * 25;
            of[i] = Lg[(15 + c) * LGS + (s >> 1)];
        }
    }
    {   // frame_level_final_tech_logits [B][T][25]: 3200 floats
        float* ofr = out + (size_t)NB * NS * 40 + ((size_t)b * NTF + tt0) * 25;
        for (int i = t; i < 3200; i += BLOCK) {
            int s = i / 25, c = i - s * 25;
            ofr[i] = Lg[(15 + c) * LGS + s];
        }
    }
}

extern "C" void kernel_launch(void* const* d_in, const int* in_sizes, int n_in,
                              void* d_out, int out_size, void* d_ws, size_t ws_size,
                              hipStream_t stream)
{
    const float* x  = (const float*)d_in[0];
    const float* Wg = (const float*)d_in[1];
    const float* bg = (const float*)d_in[2];
    const float* Wt = (const float*)d_in[3];
    const float* bt = (const float*)d_in[4];
    const float* Wf = (const float*)d_in[5];
    const float* bf = (const float*)d_in[6];
    float* Wp3  = (float*)d_ws;          // 40*512*4 = 80 KB packed weights
    float* outp = (float*)d_out;

    hipLaunchKernelGGL(pack_w_kernel, dim3((NCOL * ND + 255) / 256), dim3(256), 0, stream,
                       Wg, Wt, Wf, Wp3);
    hipLaunchKernelGGL(hier_main, dim3((NB * NTF) / ROWSB), dim3(BLOCK), 0, stream,
                       x, bg, bt, bf, Wp3, outp);
}